// Round 3
// baseline (32575.558 us; speedup 1.0000x reference)
//
#include <hip/hip_runtime.h>

// B=2048, T=128, N=64, H=128
// inputs: 0 X(2048,128,64) 1 W_attn1(128,384) 2 b_attn1(128) 3 w_attn2(128)
//         4 b_attn2(1)[unused: softmax shift-invariant] 5 W_ih(512,64) 6 W_hh(512,128)
//         7 b_ih(512) 8 b_hh(512)
// output: (2048,128,128) f32
// ws: Wt[128][128] @0 | Wcat[512][192] @16384 | prex[2048*64*128] @114688 (floats)

#define LOG2E 1.44269504088896340736f

__device__ __forceinline__ float rcpf(float x){ return __builtin_amdgcn_rcpf(x); }
__device__ __forceinline__ float fast_exp(float x){ return __builtin_exp2f(x * LOG2E); }
__device__ __forceinline__ float fast_tanh(float x){
  float e = __builtin_exp2f(x * (2.0f * LOG2E));
  return 1.0f - 2.0f * rcpf(e + 1.0f);
}
__device__ __forceinline__ float fast_sig(float x){
  float e = __builtin_exp2f(x * (-LOG2E));
  return rcpf(1.0f + e);
}

// ---------------- k0a: Wt[t][k] = W1x[k][t] ----------------
__global__ __launch_bounds__(256) void k0_wt(const float* __restrict__ Wat,
                                             float* __restrict__ Wt){
  int idx = blockIdx.x*256 + threadIdx.x;   // 16384
  int t = idx >> 7, k = idx & 127;
  Wt[idx] = Wat[k*384 + 256 + t];
}

// ---------------- k0b: Wcat[g][0..192] = [Wih[g] | Whh[g]] ----------------
__global__ __launch_bounds__(192) void k0_wcat(const float* __restrict__ Wih,
                                               const float* __restrict__ Whh,
                                               float* __restrict__ Wcat){
  int g = blockIdx.x, c = threadIdx.x;      // 512 x 192
  Wcat[g*192 + c] = (c < 64) ? Wih[g*64 + c] : Whh[g*128 + (c-64)];
}

// ---------------- k1: prex[b][n][k] = sum_t X[b][t][n]*W1x[k][t] + b1[k] ----
__global__ __launch_bounds__(256) void k1_prex(const float* __restrict__ X,
                                               const float* __restrict__ Wt,
                                               const float* __restrict__ b1,
                                               float* __restrict__ prex){
  __shared__ float Xs[128][64];
  const int tid = threadIdx.x;
  const long b = blockIdx.x;
  {
    const float4* X4 = (const float4*)(X + b*8192);
    float4* Xs4 = (float4*)&Xs[0][0];
    #pragma unroll
    for (int i=0;i<8;i++) Xs4[tid + i*256] = X4[tid + i*256];
  }
  __syncthreads();
  const int nq = tid >> 4, kq = tid & 15;
  float acc[4][8];
  #pragma unroll
  for (int n=0;n<4;n++)
    #pragma unroll
    for (int k=0;k<8;k++) acc[n][k]=0.f;
  #pragma unroll 4
  for (int t=0;t<128;t++){
    float4 w0 = *(const float4*)(Wt + t*128 + kq*8);
    float4 w1 = *(const float4*)(Wt + t*128 + kq*8 + 4);
    float4 xv = *(const float4*)&Xs[t][nq*4];
    float wv[8] = {w0.x,w0.y,w0.z,w0.w,w1.x,w1.y,w1.z,w1.w};
    float xa[4] = {xv.x,xv.y,xv.z,xv.w};
    #pragma unroll
    for (int n=0;n<4;n++)
      #pragma unroll
      for (int k=0;k<8;k++) acc[n][k] = fmaf(xa[n], wv[k], acc[n][k]);
  }
  float4 bv0 = *(const float4*)(b1 + kq*8);
  float4 bv1 = *(const float4*)(b1 + kq*8 + 4);
  #pragma unroll
  for (int n=0;n<4;n++){
    float* dst = prex + (b*64 + nq*4 + n)*128 + kq*8;
    *(float4*)(dst)   = make_float4(acc[n][0]+bv0.x, acc[n][1]+bv0.y,
                                    acc[n][2]+bv0.z, acc[n][3]+bv0.w);
    *(float4*)(dst+4) = make_float4(acc[n][4]+bv1.x, acc[n][5]+bv1.y,
                                    acc[n][6]+bv1.z, acc[n][7]+bv1.w);
  }
}

// ---------------- k2: persistent recurrent kernel ----------------
// 256 blocks x 1024 threads, 8 batches/block, 128 steps inside.
// Weights streamed from L2 each step (no register hoard -> no spill).
// Reductions via LDS transpose buffers (minimal shfl traffic).
__global__ __launch_bounds__(1024) void k2_lstm(const float* __restrict__ X,
                                                const float* __restrict__ Wat,
                                                const float* __restrict__ Wcat,
                                                const float* __restrict__ w2,
                                                const float* __restrict__ bih,
                                                const float* __restrict__ bhh,
                                                const float* __restrict__ prex,
                                                float* __restrict__ out){
  const int tid = threadIdx.x;
  const long b0 = (long)blockIdx.x * 8;

  __shared__ float st[2][8][132];   // [0]=h, [1]=c  (pad 132 vs bank conflicts)
  __shared__ float aa[8][132];      // attn pre-act h/c part
  __shared__ float act[8][204];     // [0..64)=x_tilde, [64..192)=h copy
  __shared__ union {
    float ep[512][36];              // P2 partials: [b*64+n][k4]
    float gp[4][8][516];            // P4 partials: [slice][b][gate]
  } u;
  __shared__ float w2s[128];
  __shared__ float blds[512];

  for (int i = tid; i < 2*8*132; i += 1024) (&st[0][0][0])[i] = 0.f;
  for (int i = tid; i < 8*204;   i += 1024) (&act[0][0])[i]   = 0.f;
  if (tid < 128) w2s[tid] = w2[tid];
  if (tid < 512) blds[tid] = bih[tid] + bhh[tid];
  __syncthreads();

  // P1: tid = kg*32 + b*4 + cq   (kg: 4 attn-rows, cq: contraction quarter)
  const int p1_kg = tid >> 5;
  const int p1_b  = (tid >> 2) & 7;
  const int p1_cq = tid & 3;
  const float* p1_w = Wat + (p1_kg*4)*384 + p1_cq*64;   // [W1h|W1s] cols 0..256
  const float* p1_a = &st[p1_cq>>1][p1_b][(p1_cq&1)*64];

  // P2: tid = (half n0) | k4 ; covers prex float4-coalesced
  const int p2_k4 = tid & 31;
  const int p2_n0 = (tid >> 5) & 31;
  const float4 p2_wv = *(const float4*)&w2s[p2_k4*4];
  const float4* p2_px = (const float4*)prex + b0*2048 + tid;

  // P4: tid = gg*16 + sl*4 + bh  (8 gates, 48-contraction slice, 2 batches)
  const int p4_gg = tid >> 4;
  const int p4_sl = (tid >> 2) & 3;
  const int p4_bh = tid & 3;
  const float* p4_w = Wcat + (p4_gg*8)*192 + p4_sl*48;

  const int o_b = tid >> 7, o_j = tid & 127;
  const float bi0 = blds[o_j], bi1 = blds[o_j+128], bi2 = blds[o_j+256], bi3 = blds[o_j+384];

  for (int t = 0; t < 128; ++t) {
    // ---------- P1: aa[b][k] = h.W1h[k,:] + c.W1s[k,:]
    {
      float a0=0.f, a1=0.f, a2=0.f, a3=0.f;
      #pragma unroll
      for (int c4 = 0; c4 < 16; ++c4) {
        float4 av = *(const float4*)(p1_a + c4*4);
        float4 w0 = *(const float4*)(p1_w + 0*384 + c4*4);
        float4 w1 = *(const float4*)(p1_w + 1*384 + c4*4);
        float4 w2_ = *(const float4*)(p1_w + 2*384 + c4*4);
        float4 w3 = *(const float4*)(p1_w + 3*384 + c4*4);
        a0=fmaf(av.x,w0.x,a0); a0=fmaf(av.y,w0.y,a0); a0=fmaf(av.z,w0.z,a0); a0=fmaf(av.w,w0.w,a0);
        a1=fmaf(av.x,w1.x,a1); a1=fmaf(av.y,w1.y,a1); a1=fmaf(av.z,w1.z,a1); a1=fmaf(av.w,w1.w,a1);
        a2=fmaf(av.x,w2_.x,a2);a2=fmaf(av.y,w2_.y,a2);a2=fmaf(av.z,w2_.z,a2);a2=fmaf(av.w,w2_.w,a2);
        a3=fmaf(av.x,w3.x,a3); a3=fmaf(av.y,w3.y,a3); a3=fmaf(av.z,w3.z,a3); a3=fmaf(av.w,w3.w,a3);
      }
      a0 += __shfl_xor(a0,1,64); a1 += __shfl_xor(a1,1,64);
      a2 += __shfl_xor(a2,1,64); a3 += __shfl_xor(a3,1,64);
      a0 += __shfl_xor(a0,2,64); a1 += __shfl_xor(a1,2,64);
      a2 += __shfl_xor(a2,2,64); a3 += __shfl_xor(a3,2,64);
      if (p1_cq == 0) *(float4*)&aa[p1_b][p1_kg*4] = make_float4(a0,a1,a2,a3);
    }
    __syncthreads();

    // ---------- P2: ep[b*64+n][k4] = sum over 4 k's of tanh(prex+aa)*w2
    {
      #pragma unroll
      for (int i = 0; i < 16; ++i) {
        float4 pv = p2_px[i*1024];
        float4 av = *(const float4*)&aa[i>>1][p2_k4*4];
        float s = fmaf(fast_tanh(pv.x+av.x), p2_wv.x,
                  fmaf(fast_tanh(pv.y+av.y), p2_wv.y,
                  fmaf(fast_tanh(pv.z+av.z), p2_wv.z,
                       fast_tanh(pv.w+av.w) * p2_wv.w)));
        u.ep[(i>>1)*64 + p2_n0 + 32*(i&1)][p2_k4] = s;
      }
    }
    __syncthreads();

    // ---------- P3: reduce k4, softmax over n, x_tilde
    if (tid < 512) {
      int b = tid >> 6, n = tid & 63;
      float e = 0.f;
      #pragma unroll
      for (int j = 0; j < 8; ++j) {
        float4 v = *(const float4*)&u.ep[tid][j*4];
        e += (v.x+v.y)+(v.z+v.w);
      }
      float mx = e;
      #pragma unroll
      for (int m=32;m>=1;m>>=1) mx = fmaxf(mx, __shfl_xor(mx,m,64));
      float p = fast_exp(e - mx);
      float sm = p;
      #pragma unroll
      for (int m=32;m>=1;m>>=1) sm += __shfl_xor(sm,m,64);
      act[b][n] = p * rcpf(sm) * X[(b0+b)*8192 + (long)t*64 + n];
    }
    __syncthreads();

    // ---------- P4: gate partials gp[sl][b][g] over act=[xt|h]
    {
      float pc[8][2];
      #pragma unroll
      for (int gi=0; gi<8; ++gi) { pc[gi][0]=0.f; pc[gi][1]=0.f; }
      #pragma unroll
      for (int c4 = 0; c4 < 12; ++c4) {
        float4 A0 = *(const float4*)&act[p4_bh*2+0][p4_sl*48 + c4*4];
        float4 A1 = *(const float4*)&act[p4_bh*2+1][p4_sl*48 + c4*4];
        #pragma unroll
        for (int gi = 0; gi < 8; ++gi) {
          float4 w = *(const float4*)(p4_w + gi*192 + c4*4);
          pc[gi][0]=fmaf(A0.x,w.x,pc[gi][0]); pc[gi][0]=fmaf(A0.y,w.y,pc[gi][0]);
          pc[gi][0]=fmaf(A0.z,w.z,pc[gi][0]); pc[gi][0]=fmaf(A0.w,w.w,pc[gi][0]);
          pc[gi][1]=fmaf(A1.x,w.x,pc[gi][1]); pc[gi][1]=fmaf(A1.y,w.y,pc[gi][1]);
          pc[gi][1]=fmaf(A1.z,w.z,pc[gi][1]); pc[gi][1]=fmaf(A1.w,w.w,pc[gi][1]);
        }
      }
      #pragma unroll
      for (int bb = 0; bb < 2; ++bb) {
        *(float4*)&u.gp[p4_sl][p4_bh*2+bb][p4_gg*8+0] =
            make_float4(pc[0][bb],pc[1][bb],pc[2][bb],pc[3][bb]);
        *(float4*)&u.gp[p4_sl][p4_bh*2+bb][p4_gg*8+4] =
            make_float4(pc[4][bb],pc[5][bb],pc[6][bb],pc[7][bb]);
      }
    }
    __syncthreads();

    // ---------- P4b: sum slices, pointwise LSTM, write out
    {
      float s0=bi0, s1=bi1, s2=bi2, s3=bi3;
      #pragma unroll
      for (int sl = 0; sl < 4; ++sl) {
        s0 += u.gp[sl][o_b][o_j];
        s1 += u.gp[sl][o_b][o_j+128];
        s2 += u.gp[sl][o_b][o_j+256];
        s3 += u.gp[sl][o_b][o_j+384];
      }
      float ig = fast_sig(s0), fg = fast_sig(s1);
      float gg_ = fast_tanh(s2), og = fast_sig(s3);
      float cold = st[1][o_b][o_j];
      float cn = fmaf(fg, cold, ig*gg_);
      float hn = og * fast_tanh(cn);
      st[1][o_b][o_j] = cn;
      st[0][o_b][o_j] = hn;
      act[o_b][64 + o_j] = hn;
      out[(b0+o_b)*16384 + (long)t*128 + o_j] = hn;
    }
    __syncthreads();
  }
}

extern "C" void kernel_launch(void* const* d_in, const int* in_sizes, int n_in,
                              void* d_out, int out_size, void* d_ws, size_t ws_size,
                              hipStream_t stream) {
  const float* X   = (const float*)d_in[0];
  const float* Wat = (const float*)d_in[1];
  const float* b1  = (const float*)d_in[2];
  const float* w2  = (const float*)d_in[3];
  const float* Wih = (const float*)d_in[5];
  const float* Whh = (const float*)d_in[6];
  const float* bih = (const float*)d_in[7];
  const float* bhh = (const float*)d_in[8];
  float* out  = (float*)d_out;
  float* Wt   = (float*)d_ws;            // 16384 floats
  float* Wcat = Wt + 16384;              // 98304 floats
  float* prex = Wcat + 98304;            // 16777216 floats

  k0_wt  <<<64,   256, 0, stream>>>(Wat, Wt);
  k0_wcat<<<512,  192, 0, stream>>>(Wih, Whh, Wcat);
  k1_prex<<<2048, 256, 0, stream>>>(X, Wt, b1, prex);
  k2_lstm<<<256, 1024, 0, stream>>>(X, Wat, Wcat, w2, bih, bhh, prex, out);
}